// Round 3
// baseline (829.574 us; speedup 1.0000x reference)
//
#include <hip/hip_runtime.h>
#include <math.h>

#define B_   128
#define N_   1024
#define D_   256
#define G_   64
#define GSZ_ 3
#define RD_  16
#define KD_  64
#define PD_  64
#define NF_  64
#define Q_   (G_*GSZ_)   // 192

typedef __attribute__((ext_vector_type(8))) short bf16x8;   // 8 bf16 = 4 VGPRs
typedef __attribute__((ext_vector_type(4))) float f32x4;

__device__ __forceinline__ unsigned short f2bf(float f) {
    unsigned int u = __float_as_uint(f);
    u += 0x7fffu + ((u >> 16) & 1u);       // RNE
    return (unsigned short)(u >> 16);
}

// ---------------------------------------------------------------------------
// coef_kernel: S3-symmetrized filter has 2 DOF per (f,r) (diag / off-diag
// orbit). out = sum_r c1[f,r]*T1[r] + c2[f,r]*T2[r].
// ---------------------------------------------------------------------------
__global__ void coef_kernel(const float* __restrict__ filters,
                            float* __restrict__ coef) {
    int flat = blockIdx.x * 256 + threadIdx.x;
    if (flat >= NF_ * RD_) return;
    int f = flat >> 4, r = flat & 15;
    const float* F = filters + f * 144 + r;
    float diag = F[0] + F[48 + 16] + F[96 + 32];
    float all = 0.f;
#pragma unroll
    for (int u = 0; u < 3; ++u)
#pragma unroll
        for (int v = 0; v < 3; ++v) all += F[u * 48 + v * 16];
    float a = diag * (1.f / 3.f);
    float b = (all - diag) * (1.f / 6.f);
    coef[f * 16 + r] = a - b;
    coef[1024 + f * 16 + r] = b;
}

// ---------------------------------------------------------------------------
// wb_kernel: Wb[col][d] bf16, col-major-k so rel2's B staging is 16B loads.
// ---------------------------------------------------------------------------
__global__ void wb_kernel(const float* __restrict__ Wq,
                          const float* __restrict__ Wk,
                          unsigned short* __restrict__ Wb) {
    int flat = blockIdx.x * 256 + threadIdx.x;     // [0, 2048*256)
    int d = flat & 255, col = flat >> 8;
    int ch = col & 1023;
    const float* W = (col >> 10) ? Wk : Wq;
    float v = W[((size_t)(ch >> 6) * 256 + d) * 64 + (ch & 63)];
    Wb[(size_t)col * 256 + d] = f2bf(v);
}

// ---------------------------------------------------------------------------
// qeb_kernel: qeb = bf16(query_emb * beta), beta = 0.125 (exact pow2 scale)
// ---------------------------------------------------------------------------
__global__ void qeb_kernel(const float* __restrict__ qe,
                           unsigned short* __restrict__ qeb) {
    int i = blockIdx.x * 256 + threadIdx.x;
    if (i < Q_ * KD_) qeb[i] = f2bf(qe[i] * 0.125f);
}

// ---------------------------------------------------------------------------
// k_proj: k = x@Wk_map + PE  -> kb bf16 [b][n][kd]  (LDS-transposed store)
//         also emits xTb bf16 [b][d][n] from its staged x tiles.
// ---------------------------------------------------------------------------
__global__ __launch_bounds__(256)
void k_proj_kernel(const float* __restrict__ x,
                   const float* __restrict__ Wk_map,
                   unsigned short* __restrict__ kb,
                   unsigned short* __restrict__ xTb) {
    __shared__ alignas(16) unsigned char smraw[256*33*4 + 32*64*4];
    float (*xs)[33]  = (float(*)[33])smraw;
    float (*wsm)[64] = (float(*)[64])(smraw + 256*33*4);

    int b  = blockIdx.y;
    int n0 = blockIdx.x * 256;
    int t  = threadIdx.x;

    float acc[64];
#pragma unroll
    for (int i = 0; i < 64; ++i) acc[i] = 0.f;

    for (int dc = 0; dc < 8; ++dc) {
#pragma unroll
        for (int i = 0; i < 32; ++i) {
            int flat = i * 256 + t;
            int nl = flat >> 5, dl = flat & 31;
            xs[nl][dl] = x[((size_t)b * N_ + n0 + nl) * D_ + dc * 32 + dl];
        }
#pragma unroll
        for (int i = 0; i < 8; ++i) {
            int flat = i * 256 + t;
            int dl = flat >> 6, kd = flat & 63;
            wsm[dl][kd] = Wk_map[(dc * 32 + dl) * KD_ + kd];
        }
        __syncthreads();
#pragma unroll 4
        for (int dl = 0; dl < 32; ++dl) {
            float xv = xs[t][dl];
#pragma unroll
            for (int kd = 0; kd < 64; ++kd)
                acc[kd] += xv * wsm[dl][kd];
        }
        // emit xTb[b][d][n0+t] for this d-chunk (coalesced over t)
#pragma unroll 8
        for (int dl = 0; dl < 32; ++dl)
            xTb[((size_t)b * D_ + dc * 32 + dl) * N_ + n0 + t] = f2bf(xs[t][dl]);
        __syncthreads();
    }

    // PE + bf16, transpose through LDS (alias xs region), coalesced store.
    unsigned short (*kbs)[66] = (unsigned short(*)[66])smraw;
    int n = n0 + t;
#pragma unroll 4
    for (int kd = 0; kd < 64; kd += 2) {
        float ex    = -2.0f * (float)(kd >> 1) / (float)KD_ * logf(10000.0f);
        float freq  = expf(ex);
        float angle = (float)n * freq;
        unsigned int u = (unsigned int)f2bf(acc[kd] + sinf(angle)) |
                         ((unsigned int)f2bf(acc[kd + 1] + cosf(angle)) << 16);
        *(unsigned int*)(&kbs[t][kd]) = u;
    }
    __syncthreads();
#pragma unroll
    for (int i = 0; i < 32; ++i) {
        int flat = i * 256 + t;
        int nl = flat >> 5, kdp = flat & 31;
        unsigned int u = *(const unsigned int*)(&kbs[nl][kdp * 2]);
        *(unsigned int*)(kb + ((size_t)b * N_ + n0 + nl) * KD_ + kdp * 2) = u;
    }
}

// ---------------------------------------------------------------------------
// attn2: per block = (b, q-half of 96). Flash-style over n-chunks of 64:
//   S = qe@k^T (MFMA) -> exp (no max-sub: logits bounded tiny) -> Ps (LDS,
//   A-layout round trip) -> gobj += Ps@xT (MFMA). Row sums accumulated per
//   lane; normalization in the epilogue. All LDS pitches 72 (144B, 16B-align).
// ---------------------------------------------------------------------------
#define KBP 72
#define XTP 72
#define PSP 72

__global__ __launch_bounds__(256, 2)
void attn2_kernel(const unsigned short* __restrict__ qeb,
                  const unsigned short* __restrict__ kb,
                  const unsigned short* __restrict__ xTb,
                  unsigned short* __restrict__ gobj) {
    __shared__ unsigned short kbs[64 * KBP];
    __shared__ unsigned short xts[256 * XTP];
    __shared__ unsigned short ps [96 * PSP];
    __shared__ float Rs[96][4];
    __shared__ float invs[96];

    int b = blockIdx.x >> 1, qh = blockIdx.x & 1;
    int t = threadIdx.x, w = t >> 6, lane = t & 63;
    int quad = lane >> 4, lcol = lane & 15;
    int q0 = qh * 96;

    // qe A-fragments (persistent): m = lane&15, k = ks*32 + quad*8 + j
    bf16x8 qef[6][2];
#pragma unroll
    for (int mt = 0; mt < 6; ++mt)
#pragma unroll
        for (int ks = 0; ks < 2; ++ks)
            qef[mt][ks] = *(const bf16x8*)(qeb + (q0 + mt * 16 + lcol) * KD_ + ks * 32 + quad * 8);

    f32x4 acc[4][6];
#pragma unroll
    for (int i = 0; i < 4; ++i)
#pragma unroll
        for (int mt = 0; mt < 6; ++mt) acc[i][mt] = (f32x4)(0.f);
    float rsum[6][4];
#pragma unroll
    for (int mt = 0; mt < 6; ++mt)
#pragma unroll
        for (int r = 0; r < 4; ++r) rsum[mt][r] = 0.f;

    const unsigned short* kbB = kb + (size_t)b * N_ * KD_;
    const unsigned short* xtB = xTb + (size_t)b * D_ * N_;

    for (int c = 0; c < 16; ++c) {
        __syncthreads();   // prev chunk's PV reads of xts/ps done
        // stage kb chunk: 64 n-rows x 64 kd
#pragma unroll
        for (int i = 0; i < 2; ++i) {
            int flat = i * 256 + t;
            int row = flat >> 3, seg = flat & 7;
            *(uint4*)(kbs + row * KBP + seg * 8) =
                *(const uint4*)(kbB + (size_t)(c * 64 + row) * KD_ + seg * 8);
        }
        // stage xT chunk: 256 d-rows x 64 n
#pragma unroll
        for (int i = 0; i < 8; ++i) {
            int flat = i * 256 + t;
            int row = flat >> 3, seg = flat & 7;
            *(uint4*)(xts + row * XTP + seg * 8) =
                *(const uint4*)(xtB + (size_t)row * N_ + c * 64 + seg * 8);
        }
        __syncthreads();

        // S: wave w covers n-tile w (cols), 6 m-tiles
        f32x4 s[6];
#pragma unroll
        for (int mt = 0; mt < 6; ++mt) s[mt] = (f32x4)(0.f);
#pragma unroll
        for (int ks = 0; ks < 2; ++ks) {
            bf16x8 bf = *(const bf16x8*)(kbs + (w * 16 + lcol) * KBP + ks * 32 + quad * 8);
#pragma unroll
            for (int mt = 0; mt < 6; ++mt)
                s[mt] = __builtin_amdgcn_mfma_f32_16x16x32_bf16(qef[mt][ks], bf, s[mt], 0, 0, 0);
        }
        // exp + Ps + rowsum partials. C-layout: row = quad*4+r, col = lcol.
#pragma unroll
        for (int mt = 0; mt < 6; ++mt)
#pragma unroll
            for (int r = 0; r < 4; ++r) {
                float e = __expf(s[mt][r]);
                rsum[mt][r] += e;
                ps[(mt * 16 + quad * 4 + r) * PSP + w * 16 + lcol] = f2bf(e);
            }
        __syncthreads();

        // PV: wave w covers d-tiles {w, 4+w, 8+w, 12+w}
#pragma unroll
        for (int ks = 0; ks < 2; ++ks) {
            bf16x8 af[6];
#pragma unroll
            for (int mt = 0; mt < 6; ++mt)
                af[mt] = *(const bf16x8*)(ps + (mt * 16 + lcol) * PSP + ks * 32 + quad * 8);
#pragma unroll
            for (int i = 0; i < 4; ++i) {
                int dt = i * 4 + w;
                bf16x8 bf = *(const bf16x8*)(xts + (dt * 16 + lcol) * XTP + ks * 32 + quad * 8);
#pragma unroll
                for (int mt = 0; mt < 6; ++mt)
                    acc[i][mt] = __builtin_amdgcn_mfma_f32_16x16x32_bf16(af[mt], bf, acc[i][mt], 0, 0, 0);
            }
        }
    }

    // rowsum: reduce over the 16 col-lanes, combine waves via LDS
#pragma unroll
    for (int mt = 0; mt < 6; ++mt)
#pragma unroll
        for (int r = 0; r < 4; ++r) {
            float v = rsum[mt][r];
            v += __shfl_xor(v, 1, 64);
            v += __shfl_xor(v, 2, 64);
            v += __shfl_xor(v, 4, 64);
            v += __shfl_xor(v, 8, 64);
            rsum[mt][r] = v;
        }
    if (lcol == 0) {
#pragma unroll
        for (int mt = 0; mt < 6; ++mt)
#pragma unroll
            for (int r = 0; r < 4; ++r)
                Rs[mt * 16 + quad * 4 + r][w] = rsum[mt][r];
    }
    __syncthreads();
    if (t < 96) invs[t] = 1.0f / (Rs[t][0] + Rs[t][1] + Rs[t][2] + Rs[t][3]);
    __syncthreads();

    // normalize + bf16 store
    unsigned short* gB = gobj + ((size_t)b * Q_ + q0) * D_;
#pragma unroll
    for (int i = 0; i < 4; ++i) {
        int dt = i * 4 + w;
#pragma unroll
        for (int mt = 0; mt < 6; ++mt)
#pragma unroll
            for (int r = 0; r < 4; ++r) {
                int q = mt * 16 + quad * 4 + r;
                gB[q * D_ + dt * 16 + lcol] = f2bf(acc[i][mt][r] * invs[q]);
            }
    }
}

// ---------------------------------------------------------------------------
// rel2: per block 16 (b,g). A = bf16 gobj rows padded 3->4. For each r/half:
// stage W tile, MFMA Z, T1/T2 from C-frags, shfl-reduce over p, coef dot.
// ---------------------------------------------------------------------------
#define APITCH 264

__global__ __launch_bounds__(256, 2)
void rel2_kernel(const unsigned short* __restrict__ gobj,
                 const unsigned short* __restrict__ Wb,
                 const float* __restrict__ coef,
                 float* __restrict__ out) {
    __shared__ unsigned short As[64 * APITCH];
    __shared__ unsigned short Ws[64 * APITCH];
    __shared__ float Tp[4 * 16 * 2 * 16];   // [wave][bg][T1|T2][r]

    int t = threadIdx.x;
    int w = t >> 6, lane = t & 63;
    int quad = lane >> 4, lcol = lane & 15;
    int bg0 = blockIdx.x * 16;

    // zero n=3 padding rows
    for (int i = 0; i < 8; ++i) {
        int idx = i * 256 + t;
        int r3 = idx >> 7, c3 = idx & 127;
        ((unsigned int*)As)[(r3 * 4 + 3) * (APITCH / 2) + c3] = 0u;
    }
    // stage A: 48 bf16 gobj rows, row = (j/3)*4 + j%3
#pragma unroll
    for (int it = 0; it < 6; ++it) {
        int flat = it * 256 + t;             // [0,1536): 48 rows x 32 uint4
        int j = flat >> 5, seg = flat & 31;
        *(uint4*)(&As[((j / 3) * 4 + (j % 3)) * APITCH + seg * 8]) =
            *(const uint4*)(gobj + ((size_t)(bg0 * 3 + j)) * D_ + seg * 8);
    }

    f32x4 zq[4], zk[4];
    for (int r = 0; r < 16; ++r) {
#pragma unroll
        for (int half = 0; half < 2; ++half) {
            __syncthreads();
            const unsigned short* src = Wb + (size_t)(r + half * 16) * 64 * 256;
#pragma unroll
            for (int it = 0; it < 8; ++it) {
                int flat = it * 256 + t;
                int col = flat >> 5, ch = flat & 31;
                uint4 v = *(const uint4*)(src + col * 256 + ch * 8);
                *(uint4*)(&Ws[col * APITCH + ch * 8]) = v;
            }
            __syncthreads();

            f32x4* z = half ? zk : zq;
#pragma unroll
            for (int i = 0; i < 4; ++i) z[i] = (f32x4)(0.f);
#pragma unroll
            for (int kk = 0; kk < 8; ++kk) {
                bf16x8 bfrag = *(const bf16x8*)(&Ws[(w * 16 + lcol) * APITCH + kk * 32 + quad * 8]);
#pragma unroll
                for (int mt = 0; mt < 4; ++mt) {
                    bf16x8 afrag = *(const bf16x8*)(&As[(mt * 16 + lcol) * APITCH + kk * 32 + quad * 8]);
                    z[mt] = __builtin_amdgcn_mfma_f32_16x16x32_bf16(afrag, bfrag, z[mt], 0, 0, 0);
                }
            }
        }
#pragma unroll
        for (int mt = 0; mt < 4; ++mt) {
            float t1 = zq[mt].x * zk[mt].x + zq[mt].y * zk[mt].y +
                       zq[mt].z * zk[mt].z + zq[mt].w * zk[mt].w;
            float sq = zq[mt].x + zq[mt].y + zq[mt].z + zq[mt].w;
            float sk = zk[mt].x + zk[mt].y + zk[mt].z + zk[mt].w;
            float t2 = sq * sk;
#pragma unroll
            for (int off = 1; off < 16; off <<= 1) {
                t1 += __shfl_xor(t1, off, 64);
                t2 += __shfl_xor(t2, off, 64);
            }
            if (lcol == 0) {
                int bgl = mt * 4 + quad;
                Tp[((w * 16 + bgl) * 2 + 0) * 16 + r] = t1;
                Tp[((w * 16 + bgl) * 2 + 1) * 16 + r] = t2;
            }
        }
    }
    __syncthreads();

    int f = t & 63;
#pragma unroll
    for (int i = 0; i < 4; ++i) {
        int bgl = w * 4 + i;
        float acc = 0.f;
#pragma unroll
        for (int r = 0; r < 16; ++r) {
            float T1 = Tp[((0 * 16 + bgl) * 2 + 0) * 16 + r] + Tp[((1 * 16 + bgl) * 2 + 0) * 16 + r] +
                       Tp[((2 * 16 + bgl) * 2 + 0) * 16 + r] + Tp[((3 * 16 + bgl) * 2 + 0) * 16 + r];
            float T2 = Tp[((0 * 16 + bgl) * 2 + 1) * 16 + r] + Tp[((1 * 16 + bgl) * 2 + 1) * 16 + r] +
                       Tp[((2 * 16 + bgl) * 2 + 1) * 16 + r] + Tp[((3 * 16 + bgl) * 2 + 1) * 16 + r];
            acc += coef[f * 16 + r] * T1 + coef[1024 + f * 16 + r] * T2;
        }
        out[(size_t)(bg0 + bgl) * NF_ + f] = acc;
    }
}

// ---------------------------------------------------------------------------
extern "C" void kernel_launch(void* const* d_in, const int* in_sizes, int n_in,
                              void* d_out, int out_size, void* d_ws, size_t ws_size,
                              hipStream_t stream) {
    const float* x         = (const float*)d_in[0];
    const float* filters   = (const float*)d_in[1];
    const float* query_emb = (const float*)d_in[2];
    const float* Wk_map    = (const float*)d_in[3];
    const float* Wq        = (const float*)d_in[4];
    const float* Wk        = (const float*)d_in[5];
    float* out = (float*)d_out;

    // workspace layout (bytes):
    char* p = (char*)d_ws;
    unsigned short* xTb  = (unsigned short*)p;  p += (size_t)B_*D_*N_*2;   // 67.1 MB
    unsigned short* kbp  = (unsigned short*)p;  p += (size_t)B_*N_*KD_*2;  // 16.8 MB
    unsigned short* gobj = (unsigned short*)p;  p += (size_t)B_*Q_*D_*2;   // 12.6 MB
    unsigned short* Wb   = (unsigned short*)p;  p += (size_t)2048*256*2;   //  1.0 MB
    float*          coef = (float*)p;           p += 2048*4;
    unsigned short* qeb  = (unsigned short*)p;  p += (size_t)Q_*KD_*2;

    hipLaunchKernelGGL(k_proj_kernel, dim3(4, 128), dim3(256), 0, stream,
                       x, Wk_map, kbp, xTb);
    hipLaunchKernelGGL(qeb_kernel, dim3(48), dim3(256), 0, stream,
                       query_emb, qeb);
    hipLaunchKernelGGL(coef_kernel, dim3(4), dim3(256), 0, stream,
                       filters, coef);
    hipLaunchKernelGGL(wb_kernel, dim3(2048), dim3(256), 0, stream,
                       Wq, Wk, Wb);
    hipLaunchKernelGGL(attn2_kernel, dim3(256), dim3(256), 0, stream,
                       qeb, kbp, xTb, gobj);
    hipLaunchKernelGGL(rel2_kernel, dim3(512), dim3(256), 0, stream,
                       gobj, Wb, coef, out);
}

// Round 4
// 401.615 us; speedup vs baseline: 2.0656x; 2.0656x over previous
//
#include <hip/hip_runtime.h>
#include <math.h>

#define B_   128
#define N_   1024
#define D_   256
#define G_   64
#define GSZ_ 3
#define RD_  16
#define KD_  64
#define PD_  64
#define NF_  64
#define Q_   (G_*GSZ_)   // 192

typedef __attribute__((ext_vector_type(8))) short bf16x8;   // 8 bf16 = 4 VGPRs
typedef __attribute__((ext_vector_type(4))) float f32x4;

__device__ __forceinline__ unsigned short f2bf(float f) {
    unsigned int u = __float_as_uint(f);
    u += 0x7fffu + ((u >> 16) & 1u);       // RNE
    return (unsigned short)(u >> 16);
}

// ---------------------------------------------------------------------------
// coef_kernel: S3-symmetrized filter has 2 DOF per (f,r) (diag / off-diag
// orbit). out = sum_r c1[f,r]*T1[r] + c2[f,r]*T2[r].
// ---------------------------------------------------------------------------
__global__ void coef_kernel(const float* __restrict__ filters,
                            float* __restrict__ coef) {
    int flat = blockIdx.x * 256 + threadIdx.x;
    if (flat >= NF_ * RD_) return;
    int f = flat >> 4, r = flat & 15;
    const float* F = filters + f * 144 + r;
    float diag = F[0] + F[48 + 16] + F[96 + 32];
    float all = 0.f;
#pragma unroll
    for (int u = 0; u < 3; ++u)
#pragma unroll
        for (int v = 0; v < 3; ++v) all += F[u * 48 + v * 16];
    float a = diag * (1.f / 3.f);
    float b = (all - diag) * (1.f / 6.f);
    coef[f * 16 + r] = a - b;
    coef[1024 + f * 16 + r] = b;
}

// ---------------------------------------------------------------------------
// wb_kernel: Wb[col][d] bf16, col-major-k so rel2's B staging is 16B loads.
// ---------------------------------------------------------------------------
__global__ void wb_kernel(const float* __restrict__ Wq,
                          const float* __restrict__ Wk,
                          unsigned short* __restrict__ Wb) {
    int flat = blockIdx.x * 256 + threadIdx.x;     // [0, 2048*256)
    int d = flat & 255, col = flat >> 8;
    int ch = col & 1023;
    const float* W = (col >> 10) ? Wk : Wq;
    float v = W[((size_t)(ch >> 6) * 256 + d) * 64 + (ch & 63)];
    Wb[(size_t)col * 256 + d] = f2bf(v);
}

// ---------------------------------------------------------------------------
// qeb_kernel: qeb = bf16(query_emb * beta), beta = 0.125 (exact pow2 scale)
// ---------------------------------------------------------------------------
__global__ void qeb_kernel(const float* __restrict__ qe,
                           unsigned short* __restrict__ qeb) {
    int i = blockIdx.x * 256 + threadIdx.x;
    if (i < Q_ * KD_) qeb[i] = f2bf(qe[i] * 0.125f);
}

// ---------------------------------------------------------------------------
// wkt_kernel: WkTb[kd][d] = bf16(Wk_map[d][kd])  (one-time, 16K elems)
// ---------------------------------------------------------------------------
__global__ void wkt_kernel(const float* __restrict__ Wk_map,
                           unsigned short* __restrict__ WkTb) {
    int i = blockIdx.x * 256 + threadIdx.x;   // [0, 16384)
    int kd = i >> 8, d = i & 255;
    WkTb[kd * 256 + d] = f2bf(Wk_map[d * 64 + kd]);
}

// ---------------------------------------------------------------------------
// xt_kernel: xTb[b][d][n] = bf16(x[b][n][d]). Tile 128n x 64d through LDS.
// Loads: 256B/quarter-wave; stores: uint4/lane (256B per quarter-wave).
// ---------------------------------------------------------------------------
__global__ __launch_bounds__(256)
void xt_kernel(const float* __restrict__ x,
               unsigned short* __restrict__ xTb) {
    __shared__ float xs[128][65];
    int b = blockIdx.z, d0 = blockIdx.y * 64, n0 = blockIdx.x * 128;
    int t = threadIdx.x;
#pragma unroll
    for (int i = 0; i < 8; ++i) {
        int f = i * 256 + t;
        int row = f >> 4, c4 = f & 15;       // 128 n-rows x 16 float4
        float4 v = *(const float4*)(x + ((size_t)b * N_ + n0 + row) * D_ + d0 + c4 * 4);
        xs[row][c4 * 4 + 0] = v.x; xs[row][c4 * 4 + 1] = v.y;
        xs[row][c4 * 4 + 2] = v.z; xs[row][c4 * 4 + 3] = v.w;
    }
    __syncthreads();
#pragma unroll
    for (int i = 0; i < 4; ++i) {
        int f = i * 256 + t;
        int dr = f >> 4, seg = f & 15;       // 64 d-rows x 16 n-chunks of 8
        uint4 uv;
        unsigned int* up = (unsigned int*)&uv;
#pragma unroll
        for (int j = 0; j < 4; ++j) {
            unsigned int lo = f2bf(xs[seg * 8 + 2 * j][dr]);
            unsigned int hi = f2bf(xs[seg * 8 + 2 * j + 1][dr]);
            up[j] = lo | (hi << 16);
        }
        *(uint4*)(xTb + ((size_t)b * D_ + d0 + dr) * N_ + n0 + seg * 8) = uv;
    }
}

// ---------------------------------------------------------------------------
// kproj2: k = x@Wk_map + PE -> kb bf16 [b][n][kd], via MFMA on C[kd][n]:
//   A = WkT [kd][d-contig], B = x rows cast bf16 [n][d-contig]. PE added in
//   the C-frag epilogue, then LDS transpose to [n][kd] for coalesced stores.
// ---------------------------------------------------------------------------
#define WKP 264   // 256+8 bf16 pad, 16B-aligned rows

__global__ __launch_bounds__(256, 2)
void kproj2_kernel(const float* __restrict__ x,
                   const unsigned short* __restrict__ WkTb,
                   unsigned short* __restrict__ kb) {
    __shared__ unsigned short wkts[64 * WKP];
    __shared__ unsigned short xs[64 * WKP];
    __shared__ unsigned short Ks[64 * 72];
    int b = blockIdx.y, n0 = blockIdx.x * 64;
    int t = threadIdx.x, w = t >> 6, lane = t & 63;
    int quad = lane >> 4, lcol = lane & 15;

    // stage WkT: 64 kd-rows x 256 d bf16
#pragma unroll
    for (int i = 0; i < 8; ++i) {
        int f = i * 256 + t;
        int row = f >> 5, seg = f & 31;
        *(uint4*)(&wkts[row * WKP + seg * 8]) = *(const uint4*)(WkTb + row * 256 + seg * 8);
    }
    // stage x: 64 n-rows x 256 d fp32 -> bf16
#pragma unroll
    for (int i = 0; i < 16; ++i) {
        int f = i * 256 + t;
        int row = f >> 6, c4 = f & 63;
        float4 v = *(const float4*)(x + ((size_t)b * N_ + n0 + row) * D_ + c4 * 4);
        uint2 uv;
        uv.x = (unsigned int)f2bf(v.x) | ((unsigned int)f2bf(v.y) << 16);
        uv.y = (unsigned int)f2bf(v.z) | ((unsigned int)f2bf(v.w) << 16);
        *(uint2*)(&xs[row * WKP + c4 * 4]) = uv;
    }
    __syncthreads();

    f32x4 z[4];
#pragma unroll
    for (int mt = 0; mt < 4; ++mt) z[mt] = (f32x4)(0.f);
#pragma unroll
    for (int kk = 0; kk < 8; ++kk) {
        bf16x8 bf = *(const bf16x8*)(&xs[(w * 16 + lcol) * WKP + kk * 32 + quad * 8]);
#pragma unroll
        for (int mt = 0; mt < 4; ++mt) {
            bf16x8 af = *(const bf16x8*)(&wkts[(mt * 16 + lcol) * WKP + kk * 32 + quad * 8]);
            z[mt] = __builtin_amdgcn_mfma_f32_16x16x32_bf16(af, bf, z[mt], 0, 0, 0);
        }
    }

    // epilogue: C row = kd = mt*16+quad*4+r, col = n_local = w*16+lcol
    int nl = w * 16 + lcol;
    int n = n0 + nl;
#pragma unroll
    for (int mt = 0; mt < 4; ++mt)
#pragma unroll
        for (int r = 0; r < 4; ++r) {
            int kd = mt * 16 + quad * 4 + r;
            float freq  = expf(-(float)(kd >> 1) * (logf(10000.0f) / 32.0f));
            float angle = (float)n * freq;
            float pe    = (kd & 1) ? cosf(angle) : sinf(angle);
            Ks[nl * 72 + kd] = f2bf(z[mt][r] + pe);
        }
    __syncthreads();

    // store: 64 n-rows x 64 kd, uint4 per lane
#pragma unroll
    for (int i = 0; i < 2; ++i) {
        int f = i * 256 + t;
        int row = f >> 3, seg = f & 7;
        *(uint4*)(kb + ((size_t)b * N_ + n0 + row) * KD_ + seg * 8) =
            *(const uint4*)(&Ks[row * 72 + seg * 8]);
    }
}

// ---------------------------------------------------------------------------
// attn2: per block = (b, q-half of 96). Flash-style over n-chunks of 64:
//   S = qe@k^T (MFMA) -> exp (no max-sub: logits bounded tiny) -> Ps (LDS,
//   A-layout round trip) -> gobj += Ps@xT (MFMA). Row sums accumulated per
//   lane; normalization in the epilogue. All LDS pitches 72 (144B, 16B-align).
// ---------------------------------------------------------------------------
#define KBP 72
#define XTP 72
#define PSP 72

__global__ __launch_bounds__(256, 2)
void attn2_kernel(const unsigned short* __restrict__ qeb,
                  const unsigned short* __restrict__ kb,
                  const unsigned short* __restrict__ xTb,
                  unsigned short* __restrict__ gobj) {
    __shared__ unsigned short kbs[64 * KBP];
    __shared__ unsigned short xts[256 * XTP];
    __shared__ unsigned short ps [96 * PSP];
    __shared__ float Rs[96][4];
    __shared__ float invs[96];

    int b = blockIdx.x >> 1, qh = blockIdx.x & 1;
    int t = threadIdx.x, w = t >> 6, lane = t & 63;
    int quad = lane >> 4, lcol = lane & 15;
    int q0 = qh * 96;

    bf16x8 qef[6][2];
#pragma unroll
    for (int mt = 0; mt < 6; ++mt)
#pragma unroll
        for (int ks = 0; ks < 2; ++ks)
            qef[mt][ks] = *(const bf16x8*)(qeb + (q0 + mt * 16 + lcol) * KD_ + ks * 32 + quad * 8);

    f32x4 acc[4][6];
#pragma unroll
    for (int i = 0; i < 4; ++i)
#pragma unroll
        for (int mt = 0; mt < 6; ++mt) acc[i][mt] = (f32x4)(0.f);
    float rsum[6][4];
#pragma unroll
    for (int mt = 0; mt < 6; ++mt)
#pragma unroll
        for (int r = 0; r < 4; ++r) rsum[mt][r] = 0.f;

    const unsigned short* kbB = kb + (size_t)b * N_ * KD_;
    const unsigned short* xtB = xTb + (size_t)b * D_ * N_;

    for (int c = 0; c < 16; ++c) {
        __syncthreads();
#pragma unroll
        for (int i = 0; i < 2; ++i) {
            int flat = i * 256 + t;
            int row = flat >> 3, seg = flat & 7;
            *(uint4*)(kbs + row * KBP + seg * 8) =
                *(const uint4*)(kbB + (size_t)(c * 64 + row) * KD_ + seg * 8);
        }
#pragma unroll
        for (int i = 0; i < 8; ++i) {
            int flat = i * 256 + t;
            int row = flat >> 3, seg = flat & 7;
            *(uint4*)(xts + row * XTP + seg * 8) =
                *(const uint4*)(xtB + (size_t)row * N_ + c * 64 + seg * 8);
        }
        __syncthreads();

        f32x4 s[6];
#pragma unroll
        for (int mt = 0; mt < 6; ++mt) s[mt] = (f32x4)(0.f);
#pragma unroll
        for (int ks = 0; ks < 2; ++ks) {
            bf16x8 bf = *(const bf16x8*)(kbs + (w * 16 + lcol) * KBP + ks * 32 + quad * 8);
#pragma unroll
            for (int mt = 0; mt < 6; ++mt)
                s[mt] = __builtin_amdgcn_mfma_f32_16x16x32_bf16(qef[mt][ks], bf, s[mt], 0, 0, 0);
        }
#pragma unroll
        for (int mt = 0; mt < 6; ++mt)
#pragma unroll
            for (int r = 0; r < 4; ++r) {
                float e = __expf(s[mt][r]);
                rsum[mt][r] += e;
                ps[(mt * 16 + quad * 4 + r) * PSP + w * 16 + lcol] = f2bf(e);
            }
        __syncthreads();

#pragma unroll
        for (int ks = 0; ks < 2; ++ks) {
            bf16x8 af[6];
#pragma unroll
            for (int mt = 0; mt < 6; ++mt)
                af[mt] = *(const bf16x8*)(ps + (mt * 16 + lcol) * PSP + ks * 32 + quad * 8);
#pragma unroll
            for (int i = 0; i < 4; ++i) {
                int dt = i * 4 + w;
                bf16x8 bf = *(const bf16x8*)(xts + (dt * 16 + lcol) * XTP + ks * 32 + quad * 8);
#pragma unroll
                for (int mt = 0; mt < 6; ++mt)
                    acc[i][mt] = __builtin_amdgcn_mfma_f32_16x16x32_bf16(af[mt], bf, acc[i][mt], 0, 0, 0);
            }
        }
    }

#pragma unroll
    for (int mt = 0; mt < 6; ++mt)
#pragma unroll
        for (int r = 0; r < 4; ++r) {
            float v = rsum[mt][r];
            v += __shfl_xor(v, 1, 64);
            v += __shfl_xor(v, 2, 64);
            v += __shfl_xor(v, 4, 64);
            v += __shfl_xor(v, 8, 64);
            rsum[mt][r] = v;
        }
    if (lcol == 0) {
#pragma unroll
        for (int mt = 0; mt < 6; ++mt)
#pragma unroll
            for (int r = 0; r < 4; ++r)
                Rs[mt * 16 + quad * 4 + r][w] = rsum[mt][r];
    }
    __syncthreads();
    if (t < 96) invs[t] = 1.0f / (Rs[t][0] + Rs[t][1] + Rs[t][2] + Rs[t][3]);
    __syncthreads();

    unsigned short* gB = gobj + ((size_t)b * Q_ + q0) * D_;
#pragma unroll
    for (int i = 0; i < 4; ++i) {
        int dt = i * 4 + w;
#pragma unroll
        for (int mt = 0; mt < 6; ++mt)
#pragma unroll
            for (int r = 0; r < 4; ++r) {
                int q = mt * 16 + quad * 4 + r;
                gB[q * D_ + dt * 16 + lcol] = f2bf(acc[i][mt][r] * invs[q]);
            }
    }
}

// ---------------------------------------------------------------------------
// rel2: per block 16 (b,g). A = bf16 gobj rows padded 3->4. For each r/half:
// stage W tile, MFMA Z, T1/T2 from C-frags, shfl-reduce over p, coef dot.
// ---------------------------------------------------------------------------
#define APITCH 264

__global__ __launch_bounds__(256, 2)
void rel2_kernel(const unsigned short* __restrict__ gobj,
                 const unsigned short* __restrict__ Wb,
                 const float* __restrict__ coef,
                 float* __restrict__ out) {
    __shared__ unsigned short As[64 * APITCH];
    __shared__ unsigned short Ws[64 * APITCH];
    __shared__ float Tp[4 * 16 * 2 * 16];   // [wave][bg][T1|T2][r]

    int t = threadIdx.x;
    int w = t >> 6, lane = t & 63;
    int quad = lane >> 4, lcol = lane & 15;
    int bg0 = blockIdx.x * 16;

    for (int i = 0; i < 8; ++i) {
        int idx = i * 256 + t;
        int r3 = idx >> 7, c3 = idx & 127;
        ((unsigned int*)As)[(r3 * 4 + 3) * (APITCH / 2) + c3] = 0u;
    }
#pragma unroll
    for (int it = 0; it < 6; ++it) {
        int flat = it * 256 + t;             // [0,1536): 48 rows x 32 uint4
        int j = flat >> 5, seg = flat & 31;
        *(uint4*)(&As[((j / 3) * 4 + (j % 3)) * APITCH + seg * 8]) =
            *(const uint4*)(gobj + ((size_t)(bg0 * 3 + j)) * D_ + seg * 8);
    }

    f32x4 zq[4], zk[4];
    for (int r = 0; r < 16; ++r) {
#pragma unroll
        for (int half = 0; half < 2; ++half) {
            __syncthreads();
            const unsigned short* src = Wb + (size_t)(r + half * 16) * 64 * 256;
#pragma unroll
            for (int it = 0; it < 8; ++it) {
                int flat = it * 256 + t;
                int col = flat >> 5, ch = flat & 31;
                uint4 v = *(const uint4*)(src + col * 256 + ch * 8);
                *(uint4*)(&Ws[col * APITCH + ch * 8]) = v;
            }
            __syncthreads();

            f32x4* z = half ? zk : zq;
#pragma unroll
            for (int i = 0; i < 4; ++i) z[i] = (f32x4)(0.f);
#pragma unroll
            for (int kk = 0; kk < 8; ++kk) {
                bf16x8 bfrag = *(const bf16x8*)(&Ws[(w * 16 + lcol) * APITCH + kk * 32 + quad * 8]);
#pragma unroll
                for (int mt = 0; mt < 4; ++mt) {
                    bf16x8 afrag = *(const bf16x8*)(&As[(mt * 16 + lcol) * APITCH + kk * 32 + quad * 8]);
                    z[mt] = __builtin_amdgcn_mfma_f32_16x16x32_bf16(afrag, bfrag, z[mt], 0, 0, 0);
                }
            }
        }
#pragma unroll
        for (int mt = 0; mt < 4; ++mt) {
            float t1 = zq[mt].x * zk[mt].x + zq[mt].y * zk[mt].y +
                       zq[mt].z * zk[mt].z + zq[mt].w * zk[mt].w;
            float sq = zq[mt].x + zq[mt].y + zq[mt].z + zq[mt].w;
            float sk = zk[mt].x + zk[mt].y + zk[mt].z + zk[mt].w;
            float t2 = sq * sk;
#pragma unroll
            for (int off = 1; off < 16; off <<= 1) {
                t1 += __shfl_xor(t1, off, 64);
                t2 += __shfl_xor(t2, off, 64);
            }
            if (lcol == 0) {
                int bgl = mt * 4 + quad;
                Tp[((w * 16 + bgl) * 2 + 0) * 16 + r] = t1;
                Tp[((w * 16 + bgl) * 2 + 1) * 16 + r] = t2;
            }
        }
    }
    __syncthreads();

    int f = t & 63;
#pragma unroll
    for (int i = 0; i < 4; ++i) {
        int bgl = w * 4 + i;
        float acc = 0.f;
#pragma unroll
        for (int r = 0; r < 16; ++r) {
            float T1 = Tp[((0 * 16 + bgl) * 2 + 0) * 16 + r] + Tp[((1 * 16 + bgl) * 2 + 0) * 16 + r] +
                       Tp[((2 * 16 + bgl) * 2 + 0) * 16 + r] + Tp[((3 * 16 + bgl) * 2 + 0) * 16 + r];
            float T2 = Tp[((0 * 16 + bgl) * 2 + 1) * 16 + r] + Tp[((1 * 16 + bgl) * 2 + 1) * 16 + r] +
                       Tp[((2 * 16 + bgl) * 2 + 1) * 16 + r] + Tp[((3 * 16 + bgl) * 2 + 1) * 16 + r];
            acc += coef[f * 16 + r] * T1 + coef[1024 + f * 16 + r] * T2;
        }
        out[(size_t)(bg0 + bgl) * NF_ + f] = acc;
    }
}

// ---------------------------------------------------------------------------
extern "C" void kernel_launch(void* const* d_in, const int* in_sizes, int n_in,
                              void* d_out, int out_size, void* d_ws, size_t ws_size,
                              hipStream_t stream) {
    const float* x         = (const float*)d_in[0];
    const float* filters   = (const float*)d_in[1];
    const float* query_emb = (const float*)d_in[2];
    const float* Wk_map    = (const float*)d_in[3];
    const float* Wq        = (const float*)d_in[4];
    const float* Wk        = (const float*)d_in[5];
    float* out = (float*)d_out;

    char* p = (char*)d_ws;
    unsigned short* xTb  = (unsigned short*)p;  p += (size_t)B_*D_*N_*2;   // 67.1 MB
    unsigned short* kbp  = (unsigned short*)p;  p += (size_t)B_*N_*KD_*2;  // 16.8 MB
    unsigned short* gobj = (unsigned short*)p;  p += (size_t)B_*Q_*D_*2;   // 12.6 MB
    unsigned short* Wb   = (unsigned short*)p;  p += (size_t)2048*256*2;   //  1.0 MB
    float*          coef = (float*)p;           p += 2048*4;
    unsigned short* qeb  = (unsigned short*)p;  p += (size_t)Q_*KD_*2;
    unsigned short* WkTb = (unsigned short*)p;  p += (size_t)KD_*D_*2;     // 32 KB

    hipLaunchKernelGGL(wkt_kernel, dim3(64), dim3(256), 0, stream,
                       Wk_map, WkTb);
    hipLaunchKernelGGL(xt_kernel, dim3(8, 4, 128), dim3(256), 0, stream,
                       x, xTb);
    hipLaunchKernelGGL(kproj2_kernel, dim3(16, 128), dim3(256), 0, stream,
                       x, WkTb, kbp);
    hipLaunchKernelGGL(qeb_kernel, dim3(48), dim3(256), 0, stream,
                       query_emb, qeb);
    hipLaunchKernelGGL(coef_kernel, dim3(4), dim3(256), 0, stream,
                       filters, coef);
    hipLaunchKernelGGL(wb_kernel, dim3(2048), dim3(256), 0, stream,
                       Wq, Wk, Wb);
    hipLaunchKernelGGL(attn2_kernel, dim3(256), dim3(256), 0, stream,
                       qeb, kbp, xTb, gobj);
    hipLaunchKernelGGL(rel2_kernel, dim3(512), dim3(256), 0, stream,
                       gobj, Wb, coef, out);
}

// Round 5
// 399.708 us; speedup vs baseline: 2.0754x; 1.0048x over previous
//
#include <hip/hip_runtime.h>
#include <math.h>

#define B_   128
#define N_   1024
#define D_   256
#define G_   64
#define GSZ_ 3
#define RD_  16
#define KD_  64
#define PD_  64
#define NF_  64
#define Q_   (G_*GSZ_)   // 192

typedef __attribute__((ext_vector_type(8))) short bf16x8;   // 8 bf16 = 4 VGPRs
typedef __attribute__((ext_vector_type(4))) float f32x4;

__device__ __forceinline__ unsigned short f2bf(float f) {
    unsigned int u = __float_as_uint(f);
    u += 0x7fffu + ((u >> 16) & 1u);       // RNE
    return (unsigned short)(u >> 16);
}

// ---------------------------------------------------------------------------
// coef_kernel: S3-symmetrized filter has 2 DOF per (f,r) (diag / off-diag
// orbit). out = sum_r c1[f,r]*T1[r] + c2[f,r]*T2[r].
// ---------------------------------------------------------------------------
__global__ void coef_kernel(const float* __restrict__ filters,
                            float* __restrict__ coef) {
    int flat = blockIdx.x * 256 + threadIdx.x;
    if (flat >= NF_ * RD_) return;
    int f = flat >> 4, r = flat & 15;
    const float* F = filters + f * 144 + r;
    float diag = F[0] + F[48 + 16] + F[96 + 32];
    float all = 0.f;
#pragma unroll
    for (int u = 0; u < 3; ++u)
#pragma unroll
        for (int v = 0; v < 3; ++v) all += F[u * 48 + v * 16];
    float a = diag * (1.f / 3.f);
    float b = (all - diag) * (1.f / 6.f);
    coef[f * 16 + r] = a - b;
    coef[1024 + f * 16 + r] = b;
}

// ---------------------------------------------------------------------------
// wb_kernel: Wb[col][d] bf16, col = qk*1024 + r*64 + p, d contiguous ->
// rel3 B-frags are 16B contiguous global loads (quads form 64B lines).
// ---------------------------------------------------------------------------
__global__ void wb_kernel(const float* __restrict__ Wq,
                          const float* __restrict__ Wk,
                          unsigned short* __restrict__ Wb) {
    int flat = blockIdx.x * 256 + threadIdx.x;     // [0, 2048*256)
    int d = flat & 255, col = flat >> 8;
    int ch = col & 1023;
    const float* W = (col >> 10) ? Wk : Wq;
    float v = W[((size_t)(ch >> 6) * 256 + d) * 64 + (ch & 63)];
    Wb[(size_t)col * 256 + d] = f2bf(v);
}

// ---------------------------------------------------------------------------
// qeb_kernel: qeb = bf16(query_emb * beta), beta = 0.125 (exact pow2 scale)
// ---------------------------------------------------------------------------
__global__ void qeb_kernel(const float* __restrict__ qe,
                           unsigned short* __restrict__ qeb) {
    int i = blockIdx.x * 256 + threadIdx.x;
    if (i < Q_ * KD_) qeb[i] = f2bf(qe[i] * 0.125f);
}

// ---------------------------------------------------------------------------
// wkt_kernel: WkTb[kd][d] = bf16(Wk_map[d][kd])  (one-time, 16K elems)
// ---------------------------------------------------------------------------
__global__ void wkt_kernel(const float* __restrict__ Wk_map,
                           unsigned short* __restrict__ WkTb) {
    int i = blockIdx.x * 256 + threadIdx.x;   // [0, 16384)
    int kd = i >> 8, d = i & 255;
    WkTb[kd * 256 + d] = f2bf(Wk_map[d * 64 + kd]);
}

// ---------------------------------------------------------------------------
// xt_kernel: xTb[b][d][n] = bf16(x[b][n][d]). Tile 128n x 64d through LDS.
// ---------------------------------------------------------------------------
__global__ __launch_bounds__(256)
void xt_kernel(const float* __restrict__ x,
               unsigned short* __restrict__ xTb) {
    __shared__ float xs[128][65];
    int b = blockIdx.z, d0 = blockIdx.y * 64, n0 = blockIdx.x * 128;
    int t = threadIdx.x;
#pragma unroll
    for (int i = 0; i < 8; ++i) {
        int f = i * 256 + t;
        int row = f >> 4, c4 = f & 15;       // 128 n-rows x 16 float4
        float4 v = *(const float4*)(x + ((size_t)b * N_ + n0 + row) * D_ + d0 + c4 * 4);
        xs[row][c4 * 4 + 0] = v.x; xs[row][c4 * 4 + 1] = v.y;
        xs[row][c4 * 4 + 2] = v.z; xs[row][c4 * 4 + 3] = v.w;
    }
    __syncthreads();
#pragma unroll
    for (int i = 0; i < 4; ++i) {
        int f = i * 256 + t;
        int dr = f >> 4, seg = f & 15;       // 64 d-rows x 16 n-chunks of 8
        uint4 uv;
        unsigned int* up = (unsigned int*)&uv;
#pragma unroll
        for (int j = 0; j < 4; ++j) {
            unsigned int lo = f2bf(xs[seg * 8 + 2 * j][dr]);
            unsigned int hi = f2bf(xs[seg * 8 + 2 * j + 1][dr]);
            up[j] = lo | (hi << 16);
        }
        *(uint4*)(xTb + ((size_t)b * D_ + d0 + dr) * N_ + n0 + seg * 8) = uv;
    }
}

// ---------------------------------------------------------------------------
// kproj2: k = x@Wk_map + PE -> kb bf16 [b][n][kd] via MFMA on C[kd][n].
// ---------------------------------------------------------------------------
#define WKP 264   // 256+8 bf16 pad, 16B-aligned rows

__global__ __launch_bounds__(256, 2)
void kproj2_kernel(const float* __restrict__ x,
                   const unsigned short* __restrict__ WkTb,
                   unsigned short* __restrict__ kb) {
    __shared__ unsigned short wkts[64 * WKP];
    __shared__ unsigned short xs[64 * WKP];
    __shared__ unsigned short Ks[64 * 72];
    int b = blockIdx.y, n0 = blockIdx.x * 64;
    int t = threadIdx.x, w = t >> 6, lane = t & 63;
    int quad = lane >> 4, lcol = lane & 15;

#pragma unroll
    for (int i = 0; i < 8; ++i) {
        int f = i * 256 + t;
        int row = f >> 5, seg = f & 31;
        *(uint4*)(&wkts[row * WKP + seg * 8]) = *(const uint4*)(WkTb + row * 256 + seg * 8);
    }
#pragma unroll
    for (int i = 0; i < 16; ++i) {
        int f = i * 256 + t;
        int row = f >> 6, c4 = f & 63;
        float4 v = *(const float4*)(x + ((size_t)b * N_ + n0 + row) * D_ + c4 * 4);
        uint2 uv;
        uv.x = (unsigned int)f2bf(v.x) | ((unsigned int)f2bf(v.y) << 16);
        uv.y = (unsigned int)f2bf(v.z) | ((unsigned int)f2bf(v.w) << 16);
        *(uint2*)(&xs[row * WKP + c4 * 4]) = uv;
    }
    __syncthreads();

    f32x4 z[4];
#pragma unroll
    for (int mt = 0; mt < 4; ++mt) z[mt] = (f32x4)(0.f);
#pragma unroll
    for (int kk = 0; kk < 8; ++kk) {
        bf16x8 bf = *(const bf16x8*)(&xs[(w * 16 + lcol) * WKP + kk * 32 + quad * 8]);
#pragma unroll
        for (int mt = 0; mt < 4; ++mt) {
            bf16x8 af = *(const bf16x8*)(&wkts[(mt * 16 + lcol) * WKP + kk * 32 + quad * 8]);
            z[mt] = __builtin_amdgcn_mfma_f32_16x16x32_bf16(af, bf, z[mt], 0, 0, 0);
        }
    }

    int nl = w * 16 + lcol;
    int n = n0 + nl;
#pragma unroll
    for (int mt = 0; mt < 4; ++mt)
#pragma unroll
        for (int r = 0; r < 4; ++r) {
            int kd = mt * 16 + quad * 4 + r;
            float freq  = expf(-(float)(kd >> 1) * (logf(10000.0f) / 32.0f));
            float angle = (float)n * freq;
            float pe    = (kd & 1) ? cosf(angle) : sinf(angle);
            Ks[nl * 72 + kd] = f2bf(z[mt][r] + pe);
        }
    __syncthreads();

#pragma unroll
    for (int i = 0; i < 2; ++i) {
        int f = i * 256 + t;
        int row = f >> 3, seg = f & 7;
        *(uint4*)(kb + ((size_t)b * N_ + n0 + row) * KD_ + seg * 8) =
            *(const uint4*)(&Ks[row * 72 + seg * 8]);
    }
}

// ---------------------------------------------------------------------------
// attn3: per block = (b, q-half of 96). S and PV B-fragments loaded DIRECTLY
// from global (kb[n][kd], xTb[d][n] are both k-contiguous; quads form 64B
// lines). Only the P C->A layout LDS round-trip remains (2 barriers/chunk).
// ---------------------------------------------------------------------------
#define PSP 72

__global__ __launch_bounds__(256, 2)
void attn3_kernel(const unsigned short* __restrict__ qeb,
                  const unsigned short* __restrict__ kb,
                  const unsigned short* __restrict__ xTb,
                  unsigned short* __restrict__ gobj) {
    __shared__ unsigned short ps[96 * PSP];
    __shared__ float Rs[96][4];
    __shared__ float invs[96];

    int b = blockIdx.x >> 1, qh = blockIdx.x & 1;
    int t = threadIdx.x, w = t >> 6, lane = t & 63;
    int quad = lane >> 4, lcol = lane & 15;
    int q0 = qh * 96;

    bf16x8 qef[6][2];
#pragma unroll
    for (int mt = 0; mt < 6; ++mt)
#pragma unroll
        for (int ks = 0; ks < 2; ++ks)
            qef[mt][ks] = *(const bf16x8*)(qeb + (q0 + mt * 16 + lcol) * KD_ + ks * 32 + quad * 8);

    f32x4 acc[4][6];
#pragma unroll
    for (int i = 0; i < 4; ++i)
#pragma unroll
        for (int mt = 0; mt < 6; ++mt) acc[i][mt] = (f32x4)(0.f);
    float rsum[6][4];
#pragma unroll
    for (int mt = 0; mt < 6; ++mt)
#pragma unroll
        for (int r = 0; r < 4; ++r) rsum[mt][r] = 0.f;

    const unsigned short* kbB = kb + (size_t)b * N_ * KD_;
    const unsigned short* xtB = xTb + (size_t)b * D_ * N_;

    for (int c = 0; c < 16; ++c) {
        // S: B-frag straight from global kb[n][kd]
        f32x4 s[6];
#pragma unroll
        for (int mt = 0; mt < 6; ++mt) s[mt] = (f32x4)(0.f);
#pragma unroll
        for (int ks = 0; ks < 2; ++ks) {
            bf16x8 bf = *(const bf16x8*)(kbB + (size_t)(c * 64 + w * 16 + lcol) * KD_ + ks * 32 + quad * 8);
#pragma unroll
            for (int mt = 0; mt < 6; ++mt)
                s[mt] = __builtin_amdgcn_mfma_f32_16x16x32_bf16(qef[mt][ks], bf, s[mt], 0, 0, 0);
        }
        // exp in-place, accumulate rowsums
#pragma unroll
        for (int mt = 0; mt < 6; ++mt)
#pragma unroll
            for (int r = 0; r < 4; ++r) {
                float e = __expf(s[mt][r]);
                s[mt][r] = e;
                rsum[mt][r] += e;
            }
        __syncthreads();   // prior chunk's PV done reading ps
#pragma unroll
        for (int mt = 0; mt < 6; ++mt)
#pragma unroll
            for (int r = 0; r < 4; ++r)
                ps[(mt * 16 + quad * 4 + r) * PSP + w * 16 + lcol] = f2bf(s[mt][r]);
        __syncthreads();

        // PV: A from ps (LDS), B straight from global xTb[d][n]
#pragma unroll
        for (int ks = 0; ks < 2; ++ks) {
            bf16x8 af[6];
#pragma unroll
            for (int mt = 0; mt < 6; ++mt)
                af[mt] = *(const bf16x8*)(ps + (mt * 16 + lcol) * PSP + ks * 32 + quad * 8);
#pragma unroll
            for (int i = 0; i < 4; ++i) {
                int dt = i * 4 + w;
                bf16x8 bf = *(const bf16x8*)(xtB + (size_t)(dt * 16 + lcol) * N_ + c * 64 + ks * 32 + quad * 8);
#pragma unroll
                for (int mt = 0; mt < 6; ++mt)
                    acc[i][mt] = __builtin_amdgcn_mfma_f32_16x16x32_bf16(af[mt], bf, acc[i][mt], 0, 0, 0);
            }
        }
    }

#pragma unroll
    for (int mt = 0; mt < 6; ++mt)
#pragma unroll
        for (int r = 0; r < 4; ++r) {
            float v = rsum[mt][r];
            v += __shfl_xor(v, 1, 64);
            v += __shfl_xor(v, 2, 64);
            v += __shfl_xor(v, 4, 64);
            v += __shfl_xor(v, 8, 64);
            rsum[mt][r] = v;
        }
    if (lcol == 0) {
#pragma unroll
        for (int mt = 0; mt < 6; ++mt)
#pragma unroll
            for (int r = 0; r < 4; ++r)
                Rs[mt * 16 + quad * 4 + r][w] = rsum[mt][r];
    }
    __syncthreads();
    if (t < 96) invs[t] = 1.0f / (Rs[t][0] + Rs[t][1] + Rs[t][2] + Rs[t][3]);
    __syncthreads();

    unsigned short* gB = gobj + ((size_t)b * Q_ + q0) * D_;
#pragma unroll
    for (int i = 0; i < 4; ++i) {
        int dt = i * 4 + w;
#pragma unroll
        for (int mt = 0; mt < 6; ++mt)
#pragma unroll
            for (int r = 0; r < 4; ++r) {
                int q = mt * 16 + quad * 4 + r;
                gB[q * D_ + dt * 16 + lcol] = f2bf(acc[i][mt][r] * invs[q]);
            }
    }
}

// ---------------------------------------------------------------------------
// rel3: per block 32 bg (A = 128 rows, padded, staged ONCE in LDS).
// Main loop has NO barriers: B-frags of Wb loaded directly from global
// (L2-resident), A-frags from LDS. Process r in pairs (zq0/zk0/zq1/zk1 =
// 128 acc VGPRs, 32 MFMA per kk per wave). Waves split the p dimension.
// ---------------------------------------------------------------------------
#define AP3 264

__global__ __launch_bounds__(256, 2)
void rel3_kernel(const unsigned short* __restrict__ gobj,
                 const unsigned short* __restrict__ Wb,
                 const float* __restrict__ coef,
                 float* __restrict__ out) {
    __shared__ unsigned short As[128 * AP3];
    __shared__ float Tp[4096];   // [w][bgl][T1|T2][r] = 4*32*2*16

    int t = threadIdx.x, w = t >> 6, lane = t & 63;
    int quad = lane >> 4, lcol = lane & 15;
    int bg0 = blockIdx.x * 32;
    int pcol = w * 16 + lcol;

    // zero padding rows (row%4==3): 32 rows x 256 cols
#pragma unroll
    for (int i = 0; i < 4; ++i) {
        int idx = i * 256 + t;
        int r3 = idx >> 5, c4 = idx & 31;
        uint4 zz; zz.x = zz.y = zz.z = zz.w = 0u;
        *(uint4*)(&As[(r3 * 4 + 3) * AP3 + c4 * 8]) = zz;
    }
    // stage 96 gobj rows, row = (j/3)*4 + j%3
#pragma unroll
    for (int i = 0; i < 12; ++i) {
        int idx = i * 256 + t;
        int j = idx >> 5, c4 = idx & 31;
        *(uint4*)(&As[((j / 3) * 4 + (j % 3)) * AP3 + c4 * 8]) =
            *(const uint4*)(gobj + ((size_t)(bg0 * 3 + j)) * 256 + c4 * 8);
    }
    __syncthreads();

    for (int rp = 0; rp < 8; ++rp) {
        f32x4 zq0[8], zq1[8], zk0[8], zk1[8];
#pragma unroll
        for (int mt = 0; mt < 8; ++mt) {
            zq0[mt] = (f32x4)(0.f); zq1[mt] = (f32x4)(0.f);
            zk0[mt] = (f32x4)(0.f); zk1[mt] = (f32x4)(0.f);
        }
        const unsigned short* bq0p = Wb + (size_t)((2 * rp) * 64 + pcol) * 256;
        const unsigned short* bq1p = Wb + (size_t)((2 * rp + 1) * 64 + pcol) * 256;
        const unsigned short* bk0p = bq0p + (size_t)1024 * 256;
        const unsigned short* bk1p = bq1p + (size_t)1024 * 256;
#pragma unroll
        for (int kk = 0; kk < 8; ++kk) {
            int co = kk * 32 + quad * 8;
            bf16x8 bq0 = *(const bf16x8*)(bq0p + co);
            bf16x8 bk0 = *(const bf16x8*)(bk0p + co);
            bf16x8 bq1 = *(const bf16x8*)(bq1p + co);
            bf16x8 bk1 = *(const bf16x8*)(bk1p + co);
#pragma unroll
            for (int mt = 0; mt < 8; ++mt) {
                bf16x8 af = *(const bf16x8*)(&As[(mt * 16 + lcol) * AP3 + co]);
                zq0[mt] = __builtin_amdgcn_mfma_f32_16x16x32_bf16(af, bq0, zq0[mt], 0, 0, 0);
                zk0[mt] = __builtin_amdgcn_mfma_f32_16x16x32_bf16(af, bk0, zk0[mt], 0, 0, 0);
                zq1[mt] = __builtin_amdgcn_mfma_f32_16x16x32_bf16(af, bq1, zq1[mt], 0, 0, 0);
                zk1[mt] = __builtin_amdgcn_mfma_f32_16x16x32_bf16(af, bk1, zk1[mt], 0, 0, 0);
            }
        }
        // epilogue: lane holds Z[bgl = mt*4+quad][n = reg][p = pcol]
#pragma unroll
        for (int rr = 0; rr < 2; ++rr) {
            int r = 2 * rp + rr;
#pragma unroll
            for (int mt = 0; mt < 8; ++mt) {
                f32x4 zq = rr ? zq1[mt] : zq0[mt];
                f32x4 zk = rr ? zk1[mt] : zk0[mt];
                float t1 = zq.x * zk.x + zq.y * zk.y + zq.z * zk.z + zq.w * zk.w;
                float sq = zq.x + zq.y + zq.z + zq.w;
                float sk = zk.x + zk.y + zk.z + zk.w;
                float t2 = sq * sk;
#pragma unroll
                for (int off = 1; off < 16; off <<= 1) {
                    t1 += __shfl_xor(t1, off, 64);
                    t2 += __shfl_xor(t2, off, 64);
                }
                if (lcol == 0) {
                    int bgl = mt * 4 + quad;
                    Tp[((w * 32 + bgl) * 2 + 0) * 16 + r] = t1;
                    Tp[((w * 32 + bgl) * 2 + 1) * 16 + r] = t2;
                }
            }
        }
    }
    __syncthreads();

    // out[bg][f] = sum_r c1*T1 + c2*T2  (T summed over 4 waves)
    int f = t & 63, g8 = t >> 6;
    float c1v[16], c2v[16];
#pragma unroll
    for (int r = 0; r < 16; ++r) {
        c1v[r] = coef[f * 16 + r];
        c2v[r] = coef[1024 + f * 16 + r];
    }
#pragma unroll
    for (int i = 0; i < 8; ++i) {
        int bgl = g8 * 8 + i;
        float a = 0.f;
#pragma unroll
        for (int r = 0; r < 16; ++r) {
            float T1 = Tp[((0 * 32 + bgl) * 2 + 0) * 16 + r] + Tp[((1 * 32 + bgl) * 2 + 0) * 16 + r] +
                       Tp[((2 * 32 + bgl) * 2 + 0) * 16 + r] + Tp[((3 * 32 + bgl) * 2 + 0) * 16 + r];
            float T2 = Tp[((0 * 32 + bgl) * 2 + 1) * 16 + r] + Tp[((1 * 32 + bgl) * 2 + 1) * 16 + r] +
                       Tp[((2 * 32 + bgl) * 2 + 1) * 16 + r] + Tp[((3 * 32 + bgl) * 2 + 1) * 16 + r];
            a += c1v[r] * T1 + c2v[r] * T2;
        }
        out[(size_t)(bg0 + bgl) * NF_ + f] = a;
    }
}

// ---------------------------------------------------------------------------
extern "C" void kernel_launch(void* const* d_in, const int* in_sizes, int n_in,
                              void* d_out, int out_size, void* d_ws, size_t ws_size,
                              hipStream_t stream) {
    const float* x         = (const float*)d_in[0];
    const float* filters   = (const float*)d_in[1];
    const float* query_emb = (const float*)d_in[2];
    const float* Wk_map    = (const float*)d_in[3];
    const float* Wq        = (const float*)d_in[4];
    const float* Wk        = (const float*)d_in[5];
    float* out = (float*)d_out;

    char* p = (char*)d_ws;
    unsigned short* xTb  = (unsigned short*)p;  p += (size_t)B_*D_*N_*2;   // 67.1 MB
    unsigned short* kbp  = (unsigned short*)p;  p += (size_t)B_*N_*KD_*2;  // 16.8 MB
    unsigned short* gobj = (unsigned short*)p;  p += (size_t)B_*Q_*D_*2;   // 12.6 MB
    unsigned short* Wb   = (unsigned short*)p;  p += (size_t)2048*256*2;   //  1.0 MB
    float*          coef = (float*)p;           p += 2048*4;
    unsigned short* qeb  = (unsigned short*)p;  p += (size_t)Q_*KD_*2;
    unsigned short* WkTb = (unsigned short*)p;  p += (size_t)KD_*D_*2;     // 32 KB

    hipLaunchKernelGGL(wkt_kernel, dim3(64), dim3(256), 0, stream,
                       Wk_map, WkTb);
    hipLaunchKernelGGL(xt_kernel, dim3(8, 4, 128), dim3(256), 0, stream,
                       x, xTb);
    hipLaunchKernelGGL(kproj2_kernel, dim3(16, 128), dim3(256), 0, stream,
                       x, WkTb, kbp);
    hipLaunchKernelGGL(qeb_kernel, dim3(48), dim3(256), 0, stream,
                       query_emb, qeb);
    hipLaunchKernelGGL(coef_kernel, dim3(4), dim3(256), 0, stream,
                       filters, coef);
    hipLaunchKernelGGL(wb_kernel, dim3(2048), dim3(256), 0, stream,
                       Wq, Wk, Wb);
    hipLaunchKernelGGL(attn3_kernel, dim3(256), dim3(256), 0, stream,
                       qeb, kbp, xTb, gobj);
    hipLaunchKernelGGL(rel3_kernel, dim3(256), dim3(256), 0, stream,
                       gobj, Wb, coef, out);
}

// Round 6
// 358.432 us; speedup vs baseline: 2.3144x; 1.1152x over previous
//
#include <hip/hip_runtime.h>
#include <math.h>

#define B_   128
#define N_   1024
#define D_   256
#define G_   64
#define GSZ_ 3
#define RD_  16
#define KD_  64
#define PD_  64
#define NF_  64
#define Q_   (G_*GSZ_)   // 192

typedef __attribute__((ext_vector_type(8))) short bf16x8;   // 8 bf16 = 4 VGPRs
typedef __attribute__((ext_vector_type(4))) float f32x4;

__device__ __forceinline__ unsigned short f2bf(float f) {
    unsigned int u = __float_as_uint(f);
    u += 0x7fffu + ((u >> 16) & 1u);       // RNE
    return (unsigned short)(u >> 16);
}

// ---------------------------------------------------------------------------
// coef_kernel: S3-symmetrized filter has 2 DOF per (f,r) (diag / off-diag
// orbit). out = sum_r c1[f,r]*T1[r] + c2[f,r]*T2[r].
// ---------------------------------------------------------------------------
__global__ void coef_kernel(const float* __restrict__ filters,
                            float* __restrict__ coef) {
    int flat = blockIdx.x * 256 + threadIdx.x;
    if (flat >= NF_ * RD_) return;
    int f = flat >> 4, r = flat & 15;
    const float* F = filters + f * 144 + r;
    float diag = F[0] + F[48 + 16] + F[96 + 32];
    float all = 0.f;
#pragma unroll
    for (int u = 0; u < 3; ++u)
#pragma unroll
        for (int v = 0; v < 3; ++v) all += F[u * 48 + v * 16];
    float a = diag * (1.f / 3.f);
    float b = (all - diag) * (1.f / 6.f);
    coef[f * 16 + r] = a - b;
    coef[1024 + f * 16 + r] = b;
}

// ---------------------------------------------------------------------------
// wb2: Wb[col][d] bf16, col = qk*1024 + r*64 + p. LDS-transposed so the
// global reads are coalesced float4 over p (one W row = 256B read by 16
// lanes), stores are uint4 rows.
// ---------------------------------------------------------------------------
__global__ __launch_bounds__(256)
void wb2_kernel(const float* __restrict__ Wq,
                const float* __restrict__ Wk,
                unsigned short* __restrict__ Wb) {
    __shared__ unsigned short wt[64 * 264];
    int qk = blockIdx.x >> 4, r = blockIdx.x & 15;
    const float* W = qk ? Wk : Wq;
    int t = threadIdx.x;
#pragma unroll
    for (int i = 0; i < 16; ++i) {
        int flat = i * 256 + t;            // 4096: 256 d x 16 p4
        int d = flat >> 4, p4 = flat & 15;
        float4 v = *(const float4*)(W + ((size_t)r * 256 + d) * 64 + p4 * 4);
        wt[(p4 * 4 + 0) * 264 + d] = f2bf(v.x);
        wt[(p4 * 4 + 1) * 264 + d] = f2bf(v.y);
        wt[(p4 * 4 + 2) * 264 + d] = f2bf(v.z);
        wt[(p4 * 4 + 3) * 264 + d] = f2bf(v.w);
    }
    __syncthreads();
#pragma unroll
    for (int i = 0; i < 8; ++i) {
        int flat = i * 256 + t;            // 2048: 64 p x 32 segs
        int p = flat >> 5, seg = flat & 31;
        *(uint4*)(Wb + ((size_t)(qk * 1024 + r * 64 + p)) * 256 + seg * 8) =
            *(const uint4*)(&wt[p * 264 + seg * 8]);
    }
}

// ---------------------------------------------------------------------------
// qeb_kernel: qeb = bf16(query_emb * beta), beta = 0.125 (exact pow2 scale)
// ---------------------------------------------------------------------------
__global__ void qeb_kernel(const float* __restrict__ qe,
                           unsigned short* __restrict__ qeb) {
    int i = blockIdx.x * 256 + threadIdx.x;
    if (i < Q_ * KD_) qeb[i] = f2bf(qe[i] * 0.125f);
}

// ---------------------------------------------------------------------------
// wkt_kernel: WkTb[kd][d] = bf16(Wk_map[d][kd])  (one-time, 16K elems)
// ---------------------------------------------------------------------------
__global__ void wkt_kernel(const float* __restrict__ Wk_map,
                           unsigned short* __restrict__ WkTb) {
    int i = blockIdx.x * 256 + threadIdx.x;   // [0, 16384)
    int kd = i >> 8, d = i & 255;
    WkTb[kd * 256 + d] = f2bf(Wk_map[d * 64 + kd]);
}

// ---------------------------------------------------------------------------
// xt_kernel: xTb[b][d][n] = bf16(x[b][n][d]). Tile 128n x 64d through LDS.
// ---------------------------------------------------------------------------
__global__ __launch_bounds__(256)
void xt_kernel(const float* __restrict__ x,
               unsigned short* __restrict__ xTb) {
    __shared__ float xs[128][65];
    int b = blockIdx.z, d0 = blockIdx.y * 64, n0 = blockIdx.x * 128;
    int t = threadIdx.x;
#pragma unroll
    for (int i = 0; i < 8; ++i) {
        int f = i * 256 + t;
        int row = f >> 4, c4 = f & 15;       // 128 n-rows x 16 float4
        float4 v = *(const float4*)(x + ((size_t)b * N_ + n0 + row) * D_ + d0 + c4 * 4);
        xs[row][c4 * 4 + 0] = v.x; xs[row][c4 * 4 + 1] = v.y;
        xs[row][c4 * 4 + 2] = v.z; xs[row][c4 * 4 + 3] = v.w;
    }
    __syncthreads();
#pragma unroll
    for (int i = 0; i < 4; ++i) {
        int f = i * 256 + t;
        int dr = f >> 4, seg = f & 15;       // 64 d-rows x 16 n-chunks of 8
        uint4 uv;
        unsigned int* up = (unsigned int*)&uv;
#pragma unroll
        for (int j = 0; j < 4; ++j) {
            unsigned int lo = f2bf(xs[seg * 8 + 2 * j][dr]);
            unsigned int hi = f2bf(xs[seg * 8 + 2 * j + 1][dr]);
            up[j] = lo | (hi << 16);
        }
        *(uint4*)(xTb + ((size_t)b * D_ + d0 + dr) * N_ + n0 + seg * 8) = uv;
    }
}

// ---------------------------------------------------------------------------
// kproj2: k = x@Wk_map + PE -> kb bf16 [b][n][kd] via MFMA on C[kd][n].
// ---------------------------------------------------------------------------
#define WKP 264   // 256+8 bf16 pad, 16B-aligned rows

__global__ __launch_bounds__(256, 2)
void kproj2_kernel(const float* __restrict__ x,
                   const unsigned short* __restrict__ WkTb,
                   unsigned short* __restrict__ kb) {
    __shared__ unsigned short wkts[64 * WKP];
    __shared__ unsigned short xs[64 * WKP];
    __shared__ unsigned short Ks[64 * 72];
    int b = blockIdx.y, n0 = blockIdx.x * 64;
    int t = threadIdx.x, w = t >> 6, lane = t & 63;
    int quad = lane >> 4, lcol = lane & 15;

#pragma unroll
    for (int i = 0; i < 8; ++i) {
        int f = i * 256 + t;
        int row = f >> 5, seg = f & 31;
        *(uint4*)(&wkts[row * WKP + seg * 8]) = *(const uint4*)(WkTb + row * 256 + seg * 8);
    }
#pragma unroll
    for (int i = 0; i < 16; ++i) {
        int f = i * 256 + t;
        int row = f >> 6, c4 = f & 63;
        float4 v = *(const float4*)(x + ((size_t)b * N_ + n0 + row) * D_ + c4 * 4);
        uint2 uv;
        uv.x = (unsigned int)f2bf(v.x) | ((unsigned int)f2bf(v.y) << 16);
        uv.y = (unsigned int)f2bf(v.z) | ((unsigned int)f2bf(v.w) << 16);
        *(uint2*)(&xs[row * WKP + c4 * 4]) = uv;
    }
    __syncthreads();

    f32x4 z[4];
#pragma unroll
    for (int mt = 0; mt < 4; ++mt) z[mt] = (f32x4)(0.f);
#pragma unroll
    for (int kk = 0; kk < 8; ++kk) {
        bf16x8 bf = *(const bf16x8*)(&xs[(w * 16 + lcol) * WKP + kk * 32 + quad * 8]);
#pragma unroll
        for (int mt = 0; mt < 4; ++mt) {
            bf16x8 af = *(const bf16x8*)(&wkts[(mt * 16 + lcol) * WKP + kk * 32 + quad * 8]);
            z[mt] = __builtin_amdgcn_mfma_f32_16x16x32_bf16(af, bf, z[mt], 0, 0, 0);
        }
    }

    int nl = w * 16 + lcol;
    int n = n0 + nl;
#pragma unroll
    for (int mt = 0; mt < 4; ++mt)
#pragma unroll
        for (int r = 0; r < 4; ++r) {
            int kd = mt * 16 + quad * 4 + r;
            float freq  = expf(-(float)(kd >> 1) * (logf(10000.0f) / 32.0f));
            float angle = (float)n * freq;
            float pe    = (kd & 1) ? cosf(angle) : sinf(angle);
            Ks[nl * 72 + kd] = f2bf(z[mt][r] + pe);
        }
    __syncthreads();

#pragma unroll
    for (int i = 0; i < 2; ++i) {
        int f = i * 256 + t;
        int row = f >> 3, seg = f & 7;
        *(uint4*)(kb + ((size_t)b * N_ + n0 + row) * KD_ + seg * 8) =
            *(const uint4*)(&Ks[row * 72 + seg * 8]);
    }
}

// ---------------------------------------------------------------------------
// attn4: per block = (b, q-half of 96), 512 threads (8 waves/CU vs attn3's
// 4). Chunks of 128 n (half the barriers). S: wave w owns n-cols w*16+lcol.
// PV: wave w owns d-tiles {w, 8+w}. B-frags straight from global (both
// k-contiguous); only the P C->A LDS round trip synchronizes.
// ---------------------------------------------------------------------------
#define PSP2 136   // 128+8

__global__ __launch_bounds__(512, 2)
void attn4_kernel(const unsigned short* __restrict__ qeb,
                  const unsigned short* __restrict__ kb,
                  const unsigned short* __restrict__ xTb,
                  unsigned short* __restrict__ gobj) {
    __shared__ unsigned short ps[96 * PSP2];
    __shared__ float Rs[96][8];
    __shared__ float invs[96];

    int b = blockIdx.x >> 1, qh = blockIdx.x & 1;
    int t = threadIdx.x, w = t >> 6, lane = t & 63;
    int quad = lane >> 4, lcol = lane & 15;
    int q0 = qh * 96;

    bf16x8 qef[6][2];
#pragma unroll
    for (int mt = 0; mt < 6; ++mt)
#pragma unroll
        for (int ks = 0; ks < 2; ++ks)
            qef[mt][ks] = *(const bf16x8*)(qeb + (q0 + mt * 16 + lcol) * KD_ + ks * 32 + quad * 8);

    f32x4 acc[2][6];
#pragma unroll
    for (int i = 0; i < 2; ++i)
#pragma unroll
        for (int mt = 0; mt < 6; ++mt) acc[i][mt] = (f32x4)(0.f);
    float rsum[6][4];
#pragma unroll
    for (int mt = 0; mt < 6; ++mt)
#pragma unroll
        for (int r = 0; r < 4; ++r) rsum[mt][r] = 0.f;

    const unsigned short* kbB = kb + (size_t)b * N_ * KD_;
    const unsigned short* xtB = xTb + (size_t)b * D_ * N_;

    for (int c = 0; c < 8; ++c) {
        // S: wave w covers n = c*128 + w*16 + lcol
        f32x4 s[6];
#pragma unroll
        for (int mt = 0; mt < 6; ++mt) s[mt] = (f32x4)(0.f);
#pragma unroll
        for (int ks = 0; ks < 2; ++ks) {
            bf16x8 bf = *(const bf16x8*)(kbB + (size_t)(c * 128 + w * 16 + lcol) * KD_ + ks * 32 + quad * 8);
#pragma unroll
            for (int mt = 0; mt < 6; ++mt)
                s[mt] = __builtin_amdgcn_mfma_f32_16x16x32_bf16(qef[mt][ks], bf, s[mt], 0, 0, 0);
        }
#pragma unroll
        for (int mt = 0; mt < 6; ++mt)
#pragma unroll
            for (int r = 0; r < 4; ++r) {
                float e = __expf(s[mt][r]);
                s[mt][r] = e;
                rsum[mt][r] += e;
            }
        __syncthreads();   // prior chunk's PV done reading ps
#pragma unroll
        for (int mt = 0; mt < 6; ++mt)
#pragma unroll
            for (int r = 0; r < 4; ++r)
                ps[(mt * 16 + quad * 4 + r) * PSP2 + w * 16 + lcol] = f2bf(s[mt][r]);
        __syncthreads();

        // PV over k = 128 n: wave w owns d-tiles {w, 8+w}
#pragma unroll
        for (int ks = 0; ks < 4; ++ks) {
            bf16x8 af[6];
#pragma unroll
            for (int mt = 0; mt < 6; ++mt)
                af[mt] = *(const bf16x8*)(ps + (mt * 16 + lcol) * PSP2 + ks * 32 + quad * 8);
#pragma unroll
            for (int i = 0; i < 2; ++i) {
                int dt = i * 8 + w;
                bf16x8 bf = *(const bf16x8*)(xtB + (size_t)(dt * 16 + lcol) * N_ + c * 128 + ks * 32 + quad * 8);
#pragma unroll
                for (int mt = 0; mt < 6; ++mt)
                    acc[i][mt] = __builtin_amdgcn_mfma_f32_16x16x32_bf16(af[mt], bf, acc[i][mt], 0, 0, 0);
            }
        }
    }

#pragma unroll
    for (int mt = 0; mt < 6; ++mt)
#pragma unroll
        for (int r = 0; r < 4; ++r) {
            float v = rsum[mt][r];
            v += __shfl_xor(v, 1, 64);
            v += __shfl_xor(v, 2, 64);
            v += __shfl_xor(v, 4, 64);
            v += __shfl_xor(v, 8, 64);
            rsum[mt][r] = v;
        }
    if (lcol == 0) {
#pragma unroll
        for (int mt = 0; mt < 6; ++mt)
#pragma unroll
            for (int r = 0; r < 4; ++r)
                Rs[mt * 16 + quad * 4 + r][w] = rsum[mt][r];
    }
    __syncthreads();
    if (t < 96) {
        float s8 = 0.f;
#pragma unroll
        for (int ww = 0; ww < 8; ++ww) s8 += Rs[t][ww];
        invs[t] = 1.0f / s8;
    }
    __syncthreads();

    unsigned short* gB = gobj + ((size_t)b * Q_ + q0) * D_;
#pragma unroll
    for (int i = 0; i < 2; ++i) {
        int dt = i * 8 + w;
#pragma unroll
        for (int mt = 0; mt < 6; ++mt)
#pragma unroll
            for (int r = 0; r < 4; ++r) {
                int q = mt * 16 + quad * 4 + r;
                gB[q * D_ + dt * 16 + lcol] = f2bf(acc[i][mt][r] * invs[q]);
            }
    }
}

// ---------------------------------------------------------------------------
// rel4: per block 16 bg (64 A-rows incl. zero-pad n=3). A-fragments hoisted
// to registers ONCE (128 VGPR); main r-loop has zero LDS ops and zero
// barriers: 2 global 16B L2-resident Wb loads + 8 MFMA per kk. Waves split
// the p dimension. ~200 VGPR -> 2 waves/SIMD, 2 blocks/CU (8 waves/CU).
// ---------------------------------------------------------------------------
#define AP4 264

__global__ __launch_bounds__(256, 2)
void rel4_kernel(const unsigned short* __restrict__ gobj,
                 const unsigned short* __restrict__ Wb,
                 const float* __restrict__ coef,
                 float* __restrict__ out) {
    __shared__ unsigned short As[64 * AP4];
    __shared__ float Tp[2048];   // [w][bgl(16)][T1|T2][r] = 4*16*2*16

    int t = threadIdx.x, w = t >> 6, lane = t & 63;
    int quad = lane >> 4, lcol = lane & 15;
    int bg0 = blockIdx.x * 16;
    int pcol = w * 16 + lcol;

    // zero pad rows (row%4==3): 16 rows x 32 uint4
#pragma unroll
    for (int i = 0; i < 2; ++i) {
        int idx = i * 256 + t;
        int r3 = idx >> 5, c4 = idx & 31;
        uint4 zz; zz.x = zz.y = zz.z = zz.w = 0u;
        *(uint4*)(&As[(r3 * 4 + 3) * AP4 + c4 * 8]) = zz;
    }
    // stage 48 gobj rows, row = (j/3)*4 + j%3
#pragma unroll
    for (int i = 0; i < 6; ++i) {
        int idx = i * 256 + t;
        int j = idx >> 5, c4 = idx & 31;
        *(uint4*)(&As[((j / 3) * 4 + (j % 3)) * AP4 + c4 * 8]) =
            *(const uint4*)(gobj + ((size_t)(bg0 * 3 + j)) * 256 + c4 * 8);
    }
    __syncthreads();

    // hoist A-fragments to registers (reused by all 16 r)
    bf16x8 af[4][8];
#pragma unroll
    for (int mt = 0; mt < 4; ++mt)
#pragma unroll
        for (int kk = 0; kk < 8; ++kk)
            af[mt][kk] = *(const bf16x8*)(&As[(mt * 16 + lcol) * AP4 + kk * 32 + quad * 8]);

    for (int r = 0; r < 16; ++r) {
        f32x4 zq[4], zk[4];
#pragma unroll
        for (int mt = 0; mt < 4; ++mt) { zq[mt] = (f32x4)(0.f); zk[mt] = (f32x4)(0.f); }
        const unsigned short* bqp = Wb + (size_t)(r * 64 + pcol) * 256;
        const unsigned short* bkp = bqp + (size_t)1024 * 256;
#pragma unroll
        for (int kk = 0; kk < 8; ++kk) {
            int co = kk * 32 + quad * 8;
            bf16x8 bq = *(const bf16x8*)(bqp + co);
            bf16x8 bk = *(const bf16x8*)(bkp + co);
#pragma unroll
            for (int mt = 0; mt < 4; ++mt) {
                zq[mt] = __builtin_amdgcn_mfma_f32_16x16x32_bf16(af[mt][kk], bq, zq[mt], 0, 0, 0);
                zk[mt] = __builtin_amdgcn_mfma_f32_16x16x32_bf16(af[mt][kk], bk, zk[mt], 0, 0, 0);
            }
        }
        // lane holds Z[bgl = mt*4+quad][n = reg][p = pcol]
#pragma unroll
        for (int mt = 0; mt < 4; ++mt) {
            float t1 = zq[mt].x * zk[mt].x + zq[mt].y * zk[mt].y +
                       zq[mt].z * zk[mt].z + zq[mt].w * zk[mt].w;
            float sq = zq[mt].x + zq[mt].y + zq[mt].z + zq[mt].w;
            float sk = zk[mt].x + zk[mt].y + zk[mt].z + zk[mt].w;
            float t2 = sq * sk;
#pragma unroll
            for (int off = 1; off < 16; off <<= 1) {
                t1 += __shfl_xor(t1, off, 64);
                t2 += __shfl_xor(t2, off, 64);
            }
            if (lcol == 0) {
                int bgl = mt * 4 + quad;
                Tp[((w * 16 + bgl) * 2 + 0) * 16 + r] = t1;
                Tp[((w * 16 + bgl) * 2 + 1) * 16 + r] = t2;
            }
        }
    }
    __syncthreads();

    // out[bg][f] = sum_r c1*T1 + c2*T2  (T summed over 4 waves)
    int f = t & 63, grp = t >> 6;
#pragma unroll
    for (int i = 0; i < 4; ++i) {
        int bgl = grp * 4 + i;
        float a = 0.f;
#pragma unroll
        for (int r = 0; r < 16; ++r) {
            float T1 = Tp[((0 * 16 + bgl) * 2 + 0) * 16 + r] + Tp[((1 * 16 + bgl) * 2 + 0) * 16 + r] +
                       Tp[((2 * 16 + bgl) * 2 + 0) * 16 + r] + Tp[((3 * 16 + bgl) * 2 + 0) * 16 + r];
            float T2 = Tp[((0 * 16 + bgl) * 2 + 1) * 16 + r] + Tp[((1 * 16 + bgl) * 2 + 1) * 16 + r] +
                       Tp[((2 * 16 + bgl) * 2 + 1) * 16 + r] + Tp[((3 * 16 + bgl) * 2 + 1) * 16 + r];
            a += coef[f * 16 + r] * T1 + coef[1024 + f * 16 + r] * T2;
        }
        out[(size_t)(bg0 + bgl) * NF_ + f] = a;
    }
}

// ---------------------------------------------------------------------------
extern "C" void kernel_launch(void* const* d_in, const int* in_sizes, int n_in,
                              void* d_out, int out_size, void* d_ws, size_t ws_size,
                              hipStream_t stream) {
    const float* x         = (const float*)d_in[0];
    const float* filters   = (const float*)d_in[1];
    const float* query_emb = (const float*)d_in[2];
    const float* Wk_map    = (const float*)d_in[3];
    const float* Wq        = (const float*)d_in[4];
    const float* Wk        = (const float*)d_in[5];
    float* out = (float*)d_out;

    char* p = (char*)d_ws;
    unsigned short* xTb  = (unsigned short*)p;  p += (size_t)B_*D_*N_*2;   // 67.1 MB
    unsigned short* kbp  = (unsigned short*)p;  p += (size_t)B_*N_*KD_*2;  // 16.8 MB
    unsigned short* gobj = (unsigned short*)p;  p += (size_t)B_*Q_*D_*2;   // 12.6 MB
    unsigned short* Wb   = (unsigned short*)p;  p += (size_t)2048*256*2;   //  1.0 MB
    float*          coef = (float*)p;           p += 2048*4;
    unsigned short* qeb  = (unsigned short*)p;  p += (size_t)Q_*KD_*2;
    unsigned short* WkTb = (unsigned short*)p;  p += (size_t)KD_*D_*2;     // 32 KB

    hipLaunchKernelGGL(wkt_kernel, dim3(64), dim3(256), 0, stream,
                       Wk_map, WkTb);
    hipLaunchKernelGGL(xt_kernel, dim3(8, 4, 128), dim3(256), 0, stream,
                       x, xTb);
    hipLaunchKernelGGL(kproj2_kernel, dim3(16, 128), dim3(256), 0, stream,
                       x, WkTb, kbp);
    hipLaunchKernelGGL(qeb_kernel, dim3(48), dim3(256), 0, stream,
                       query_emb, qeb);
    hipLaunchKernelGGL(coef_kernel, dim3(4), dim3(256), 0, stream,
                       filters, coef);
    hipLaunchKernelGGL(wb2_kernel, dim3(32), dim3(256), 0, stream,
                       Wq, Wk, Wb);
    hipLaunchKernelGGL(attn4_kernel, dim3(256), dim3(512), 0, stream,
                       qeb, kbp, xTb, gobj);
    hipLaunchKernelGGL(rel4_kernel, dim3(512), dim3(256), 0, stream,
                       gobj, Wb, coef, out);
}